// Round 11
// baseline (123.552 us; speedup 1.0000x reference)
//
#include <hip/hip_runtime.h>

// EdgeLoss: mean |sobel_edge(pred) - sobel_edge(target)| over [16,3,512,512] fp32.
// Separable Sobel: s = t+2m+b, d = b-t; gx = s[x+1]-s[x-1], gy = d[x-1]+2d[x]+d[x+1].
// One wave spans the full 512-px row (lane = 8 cols); x-halo on s/d via __shfl.
// 3-slot rolling row window, 4 rows per thread, no VGPR cap (avoid spills).
// Final reduce fused: memset d_out to 0, each block atomicAdds its scaled partial.

#define EW 512
#define EH 512
#define EPLANE (EH * EW)               // 262144
#define NPLANES 48                     // 2*8 images * 3 channels
#define TOTAL_PX (NPLANES * EPLANE)    // 12582912
#define ROWS_PT 4
#define BANDS (EH / ROWS_PT)           // 128 bands/plane
#define NWAVES (NPLANES * BANDS)       // 6144
#define BLOCKS_MAIN (NWAVES / 4)       // 1536 (4 waves/block, 24 waves/CU)

__device__ __forceinline__ void load_row8(float* a, const float* __restrict__ p,
                                          bool valid) {
    if (valid) {
        float4 c0 = *reinterpret_cast<const float4*>(p);
        float4 c1 = *reinterpret_cast<const float4*>(p + 4);
        a[0] = c0.x; a[1] = c0.y; a[2] = c0.z; a[3] = c0.w;
        a[4] = c1.x; a[5] = c1.y; a[6] = c1.z; a[7] = c1.w;
    } else {
        a[0] = a[1] = a[2] = a[3] = a[4] = a[5] = a[6] = a[7] = 0.f;
    }
}

// Sobel edge for 8 px of one row from a 3-row window, separable form.
__device__ __forceinline__ void sobel_edge8(const float* Rt, const float* Rm,
                                            const float* Rb, int lane, float* e) {
    float s[8], d[8];
#pragma unroll
    for (int j = 0; j < 8; ++j) {
        s[j] = __builtin_fmaf(2.f, Rm[j], Rt[j] + Rb[j]);
        d[j] = Rb[j] - Rt[j];
    }
    float sl = __shfl_up(s[7], 1);   sl = lane ? sl : 0.f;
    float dl = __shfl_up(d[7], 1);   dl = lane ? dl : 0.f;
    float sr = __shfl_down(s[0], 1); sr = (lane < 63) ? sr : 0.f;
    float dr = __shfl_down(d[0], 1); dr = (lane < 63) ? dr : 0.f;
#pragma unroll
    for (int i = 0; i < 8; ++i) {
        float sm = (i == 0) ? sl : s[i - 1];
        float sp = (i == 7) ? sr : s[i + 1];
        float dm = (i == 0) ? dl : d[i - 1];
        float dp = (i == 7) ? dr : d[i + 1];
        float gx = sp - sm;
        float gy = __builtin_fmaf(2.f, d[i], dm + dp);
        e[i] = __builtin_amdgcn_sqrtf(
                   __builtin_fmaf(gx, gx, __builtin_fmaf(gy, gy, 1e-6f)));
    }
}

__global__ __launch_bounds__(256) void edge_main(const float* __restrict__ pred,
                                                 const float* __restrict__ tgt,
                                                 float* __restrict__ out) {
    const int lane = threadIdx.x & 63;
    const int w = blockIdx.x * 4 + (threadIdx.x >> 6);  // wave id 0..6143
    const int plane = w >> 7;                           // 128 bands/plane
    const int band = w & 127;
    const int y0 = band << 2;
    const int x0 = lane << 3;

    const float* __restrict__ pbase = pred + plane * EPLANE + y0 * EW + x0;
    const float* __restrict__ qbase = tgt  + plane * EPLANE + y0 * EW + x0;

    // rolling window: row offset k in [-1, 4] lives in slot (k+1)%3
    float P[3][8], T[3][8];
    load_row8(P[0], pbase - EW, band > 0);   // k=-1
    load_row8(T[0], qbase - EW, band > 0);
    load_row8(P[1], pbase,      true);       // k=0
    load_row8(T[1], qbase,      true);

    float sum = 0.f;
#pragma unroll
    for (int r = 0; r < ROWS_PT; ++r) {
        const bool v = (y0 + r + 1) < EH;    // wave-uniform; false only last band r=3
        load_row8(P[(r + 2) % 3], pbase + (r + 1) * EW, v);
        load_row8(T[(r + 2) % 3], qbase + (r + 1) * EW, v);

        float ep[8], et[8];
        sobel_edge8(P[r % 3], P[(r + 1) % 3], P[(r + 2) % 3], lane, ep);
        sobel_edge8(T[r % 3], T[(r + 1) % 3], T[(r + 2) % 3], lane, et);
#pragma unroll
        for (int i = 0; i < 8; ++i)
            sum += fabsf(ep[i] - et[i]);
    }

    // wave-64 shuffle reduce
    for (int off = 32; off > 0; off >>= 1)
        sum += __shfl_down(sum, off, 64);

    __shared__ float wsum[4];
    const int wid = threadIdx.x >> 6;
    if (lane == 0) wsum[wid] = sum;
    __syncthreads();
    if (threadIdx.x == 0) {
        float bsum = wsum[0] + wsum[1] + wsum[2] + wsum[3];
        atomicAdd(out, bsum * (1.0f / (float)TOTAL_PX));
    }
}

extern "C" void kernel_launch(void* const* d_in, const int* in_sizes, int n_in,
                              void* d_out, int out_size, void* d_ws, size_t ws_size,
                              hipStream_t stream) {
    const float* pred = (const float*)d_in[0];
    const float* tgt  = (const float*)d_in[1];
    float* out = (float*)d_out;

    hipMemsetAsync(out, 0, sizeof(float), stream);   // graph-capturable memset node
    edge_main<<<BLOCKS_MAIN, 256, 0, stream>>>(pred, tgt, out);
}